// Round 1
// baseline (2900.252 us; speedup 1.0000x reference)
//
#include <hip/hip_runtime.h>
#include <hip/hip_bf16.h>

#define N_NODES 500000
#define NNZ     2000000
#define N_HE    100000
#define N_G     512
#define CH      64

// ---------------- degree counting ----------------
__global__ void k_count(const int* __restrict__ row, const int* __restrict__ col,
                        int* __restrict__ Dcnt, int* __restrict__ Bcnt) {
    int i = blockIdx.x * blockDim.x + threadIdx.x;
    int stride = gridDim.x * blockDim.x;
    for (; i < NNZ; i += stride) {
        atomicAdd(&Dcnt[row[i]], 1);
        atomicAdd(&Bcnt[col[i]], 1);
    }
}

// ---------------- graph segment bounds (batch is sorted) ----------------
__global__ void k_bounds(const int* __restrict__ batch, int* __restrict__ gstart) {
    int g = blockIdx.x * blockDim.x + threadIdx.x;
    if (g > N_G) return;
    if (g == N_G) { gstart[g] = N_NODES; return; }
    int lo = 0, hi = N_NODES;
    while (lo < hi) {
        int mid = (lo + hi) >> 1;
        if (batch[mid] < g) lo = mid + 1; else hi = mid;
    }
    gstart[g] = lo;
}

// ---------------- dense 64x64 transform: out = f(in) @ W + b ----------------
// FUSE: f(v_row) = relu(v_row * Dinv[row]) (applied to conv output feeding next layer)
template<bool FUSE>
__global__ void k_transform(const float* __restrict__ in, const float* __restrict__ W,
                            const float* __restrict__ bias, const int* __restrict__ Dcnt,
                            float* __restrict__ out) {
    __shared__ float Wl[CH * CH];
    for (int t = threadIdx.x; t < CH * CH; t += blockDim.x) Wl[t] = W[t];
    __syncthreads();
    int lane = threadIdx.x & 63;
    int wid = blockIdx.x * (blockDim.x >> 6) + (threadIdx.x >> 6);
    int nw  = gridDim.x * (blockDim.x >> 6);
    float bc = bias[lane];
    for (int r = wid; r < N_NODES; r += nw) {
        float xv = in[(size_t)r * CH + lane];
        if (FUSE) {
            int d = Dcnt[r];
            float dinv = d > 0 ? 1.0f / (float)d : 0.0f;
            xv = fmaxf(xv * dinv, 0.0f);
        }
        float acc = bc;
#pragma unroll
        for (int k = 0; k < CH; ++k) {
            float a = __shfl(xv, k);
            acc = fmaf(a, Wl[k * CH + lane], acc);
        }
        out[(size_t)r * CH + lane] = acc;
    }
}

// ---------------- node -> hyperedge scatter: m[c] += xt[r] ----------------
__global__ void k_scatter(const float* __restrict__ xt, const int* __restrict__ row,
                          const int* __restrict__ col, float* __restrict__ m) {
    int lane = threadIdx.x & 63;
    int wid = blockIdx.x * (blockDim.x >> 6) + (threadIdx.x >> 6);
    int nw  = gridDim.x * (blockDim.x >> 6);
    for (int i = wid; i < NNZ; i += nw) {
        int r = row[i], c = col[i];
        float v = xt[(size_t)r * CH + lane];
        atomicAdd(&m[(size_t)c * CH + lane], v);
    }
}

// ---------------- hyperedge -> node gather: out[r] += m[c] * Binv[c] ----------------
__global__ void k_gather(const float* __restrict__ m, const int* __restrict__ Bcnt,
                         const int* __restrict__ row, const int* __restrict__ col,
                         float* __restrict__ out) {
    int lane = threadIdx.x & 63;
    int wid = blockIdx.x * (blockDim.x >> 6) + (threadIdx.x >> 6);
    int nw  = gridDim.x * (blockDim.x >> 6);
    for (int i = wid; i < NNZ; i += nw) {
        int r = row[i], c = col[i];
        int bc = Bcnt[c];
        float binv = bc > 0 ? 1.0f / (float)bc : 0.0f;
        float v = m[(size_t)c * CH + lane] * binv;
        atomicAdd(&out[(size_t)r * CH + lane], v);
    }
}

// ---------------- pool: pooled[g] += relu(h[v] * Dinv[v]) over sorted batch ----------------
__global__ void k_pool(const float* __restrict__ h, const int* __restrict__ Dcnt,
                       const int* __restrict__ batch, float* __restrict__ pooled) {
    int lane = threadIdx.x & 63;
    int wid = blockIdx.x * (blockDim.x >> 6) + (threadIdx.x >> 6);
    int nw  = gridDim.x * (blockDim.x >> 6);
    int per = (N_NODES + nw - 1) / nw;
    int start = wid * per;
    int end = start + per; if (end > N_NODES) end = N_NODES;
    if (start >= end) return;
    float acc = 0.0f;
    int cur = batch[start];
    for (int v = start; v < end; ++v) {
        int b = batch[v];
        int d = Dcnt[v];
        float dinv = d > 0 ? 1.0f / (float)d : 0.0f;
        float val = fmaxf(h[(size_t)v * CH + lane] * dinv, 0.0f);
        if (b != cur) {
            atomicAdd(&pooled[(size_t)cur * CH + lane], acc);
            acc = 0.0f; cur = b;
        }
        acc += val;
    }
    atomicAdd(&pooled[(size_t)cur * CH + lane], acc);
}

// ---------------- final: out[g] = (pooled[g]/max(cnt,1)) . Wfc + bfc ----------------
__global__ void k_final(const float* __restrict__ pooled, const int* __restrict__ gstart,
                        const float* __restrict__ Wfc, const float* __restrict__ bfc,
                        float* __restrict__ out) {
    int g = blockIdx.x;
    int lane = threadIdx.x;  // 64 threads
    float cnt = (float)(gstart[g + 1] - gstart[g]);
    cnt = fmaxf(cnt, 1.0f);
    float s = pooled[(size_t)g * CH + lane] / cnt;
    float p = s * Wfc[lane];
#pragma unroll
    for (int off = 32; off; off >>= 1) p += __shfl_down(p, off);
    if (lane == 0) out[g] = p + bfc[0];
}

extern "C" void kernel_launch(void* const* d_in, const int* in_sizes, int n_in,
                              void* d_out, int out_size, void* d_ws, size_t ws_size,
                              hipStream_t stream) {
    const float* x     = (const float*)d_in[0];
    const int*   ei    = (const int*)d_in[1];
    const int*   batch = (const int*)d_in[2];
    const float* W1    = (const float*)d_in[3];
    const float* b1    = (const float*)d_in[4];
    const float* W2    = (const float*)d_in[5];
    const float* b2    = (const float*)d_in[6];
    const float* Wfc   = (const float*)d_in[7];
    const float* bfc   = (const float*)d_in[8];
    float* out = (float*)d_out;

    const int* row = ei;
    const int* col = ei + NNZ;

    // workspace layout
    char* ws = (char*)d_ws;
    const size_t SZ_NC = (size_t)N_NODES * CH * sizeof(float);  // 128,000,000
    const size_t SZ_M  = (size_t)N_HE * CH * sizeof(float);     //  25,600,000
    float* bufA   = (float*)(ws);
    float* bufB   = (float*)(ws + SZ_NC);
    float* bufM   = (float*)(ws + 2 * SZ_NC);
    int*   Dcnt   = (int*)  (ws + 2 * SZ_NC + SZ_M);
    int*   Bcnt   = (int*)  (ws + 2 * SZ_NC + SZ_M + (size_t)N_NODES * 4);
    int*   gstart = (int*)  (ws + 2 * SZ_NC + SZ_M + (size_t)N_NODES * 4 + (size_t)N_HE * 4);
    float* pooled = (float*)(ws + 2 * SZ_NC + SZ_M + (size_t)N_NODES * 4 + (size_t)N_HE * 4 + 4096);

    // zero what we accumulate into
    hipMemsetAsync(Dcnt, 0, (size_t)N_NODES * 4, stream);
    hipMemsetAsync(Bcnt, 0, (size_t)N_HE * 4, stream);
    hipMemsetAsync(bufM, 0, SZ_M, stream);
    hipMemsetAsync(bufB, 0, SZ_NC, stream);
    hipMemsetAsync(pooled, 0, (size_t)N_G * CH * sizeof(float), stream);

    k_count<<<2048, 256, 0, stream>>>(row, col, Dcnt, Bcnt);
    k_bounds<<<3, 256, 0, stream>>>(batch, gstart);

    // conv1: xt = x@W1+b1 -> bufA; m = scatter(bufA) -> bufM; bufB = gather(m)*Binv
    k_transform<false><<<2048, 256, 0, stream>>>(x, W1, b1, nullptr, bufA);
    k_scatter<<<4096, 256, 0, stream>>>(bufA, row, col, bufM);
    k_gather<<<4096, 256, 0, stream>>>(bufM, Bcnt, row, col, bufB);

    // conv2: xt2 = relu(bufB*Dinv)@W2+b2 -> bufA
    k_transform<true><<<2048, 256, 0, stream>>>(bufB, W2, b2, Dcnt, bufA);
    hipMemsetAsync(bufM, 0, SZ_M, stream);
    hipMemsetAsync(bufB, 0, SZ_NC, stream);
    k_scatter<<<4096, 256, 0, stream>>>(bufA, row, col, bufM);
    k_gather<<<4096, 256, 0, stream>>>(bufM, Bcnt, row, col, bufB);

    // pool (applies relu(h*Dinv)) + final projection
    k_pool<<<1024, 256, 0, stream>>>(bufB, Dcnt, batch, pooled);
    k_final<<<N_G, 64, 0, stream>>>(pooled, gstart, Wfc, bfc, out);
}

// Round 3
// 2171.990 us; speedup vs baseline: 1.3353x; 1.3353x over previous
//
#include <hip/hip_runtime.h>
#include <hip/hip_bf16.h>

#define N_NODES 500000
#define NNZ     2000000
#define N_HE    100000
#define N_G     512
#define CH      64

#define SCAN_BLOCK 256
#define SCAN_CHUNK 1024   // 4 items/thread

// ---------------- degree counting ----------------
__global__ void k_count(const int* __restrict__ row, const int* __restrict__ col,
                        int* __restrict__ Dcnt, int* __restrict__ Bcnt) {
    int i = blockIdx.x * blockDim.x + threadIdx.x;
    int stride = gridDim.x * blockDim.x;
    for (; i < NNZ; i += stride) {
        atomicAdd(&Dcnt[row[i]], 1);
        atomicAdd(&Bcnt[col[i]], 1);
    }
}

// ---------------- hierarchical exclusive scan (n <= 512*1024) ----------------
__global__ void k_scan1(const int* __restrict__ in, int n, int* __restrict__ bsums) {
    __shared__ int lds[SCAN_BLOCK];
    int base = blockIdx.x * SCAN_CHUNK;
    int t = threadIdx.x;
    int s = 0;
#pragma unroll
    for (int j = 0; j < 4; ++j) { int idx = base + t * 4 + j; if (idx < n) s += in[idx]; }
    lds[t] = s; __syncthreads();
    for (int off = SCAN_BLOCK / 2; off; off >>= 1) {
        if (t < off) lds[t] += lds[t + off];
        __syncthreads();
    }
    if (t == 0) bsums[blockIdx.x] = lds[0];
}

__global__ void k_scan2(int* __restrict__ bsums, int nb) {
    __shared__ int lds[512];
    int t = threadIdx.x;
    int v = (t < nb) ? bsums[t] : 0;
    lds[t] = v; __syncthreads();
    for (int off = 1; off < 512; off <<= 1) {
        int add = (t >= off) ? lds[t - off] : 0;
        __syncthreads();
        lds[t] += add;
        __syncthreads();
    }
    if (t < nb) bsums[t] = lds[t] - v;   // exclusive
}

__global__ void k_scan3(const int* __restrict__ in, int n, const int* __restrict__ bsums,
                        int* __restrict__ outp, int* __restrict__ cursor) {
    __shared__ int lds[SCAN_BLOCK];
    int base = blockIdx.x * SCAN_CHUNK;
    int t = threadIdx.x;
    int v[4]; int s = 0;
#pragma unroll
    for (int j = 0; j < 4; ++j) { int idx = base + t * 4 + j; v[j] = (idx < n) ? in[idx] : 0; s += v[j]; }
    lds[t] = s; __syncthreads();
    for (int off = 1; off < SCAN_BLOCK; off <<= 1) {
        int add = (t >= off) ? lds[t - off] : 0;
        __syncthreads();
        lds[t] += add;
        __syncthreads();
    }
    int pref = bsums[blockIdx.x] + lds[t] - s;   // exclusive prefix for this thread
#pragma unroll
    for (int j = 0; j < 4; ++j) {
        int idx = base + t * 4 + j;
        if (idx < n) {
            outp[idx] = pref;
            cursor[idx] = pref;
            pref += v[j];
            if (idx == n - 1) outp[n] = pref;
        }
    }
}

// ---------------- CSR placement (both directions) ----------------
__global__ void k_place(const int* __restrict__ row, const int* __restrict__ col,
                        int* __restrict__ curR, int* __restrict__ curC,
                        int* __restrict__ adjR, int* __restrict__ adjC) {
    int i = blockIdx.x * blockDim.x + threadIdx.x;
    int stride = gridDim.x * blockDim.x;
    for (; i < NNZ; i += stride) {
        int r = row[i], c = col[i];
        int pR = atomicAdd(&curR[r], 1); adjR[pR] = c;   // node -> its hyperedges
        int pC = atomicAdd(&curC[c], 1); adjC[pC] = r;   // hyperedge -> its nodes
    }
}

// ---------------- graph segment bounds (batch is sorted) ----------------
__global__ void k_bounds(const int* __restrict__ batch, int* __restrict__ gstart) {
    int g = blockIdx.x * blockDim.x + threadIdx.x;
    if (g > N_G) return;
    if (g == N_G) { gstart[g] = N_NODES; return; }
    int lo = 0, hi = N_NODES;
    while (lo < hi) {
        int mid = (lo + hi) >> 1;
        if (batch[mid] < g) lo = mid + 1; else hi = mid;
    }
    gstart[g] = lo;
}

// ---------------- dense 64x64 transform: out = in @ W + b ----------------
__global__ void k_transform(const float* __restrict__ in, const float* __restrict__ W,
                            const float* __restrict__ bias, float* __restrict__ out) {
    __shared__ float Wl[CH * CH];
    for (int t = threadIdx.x; t < CH * CH; t += blockDim.x) Wl[t] = W[t];
    __syncthreads();
    int lane = threadIdx.x & 63;
    int wid = blockIdx.x * (blockDim.x >> 6) + (threadIdx.x >> 6);
    int nw  = gridDim.x * (blockDim.x >> 6);
    float bc = bias[lane];
    for (int r = wid; r < N_NODES; r += nw) {
        float xv = in[(size_t)r * CH + lane];
        float acc = bc;
#pragma unroll
        for (int k = 0; k < CH; ++k)
            acc = fmaf(__shfl(xv, k), Wl[k * CH + lane], acc);
        out[(size_t)r * CH + lane] = acc;
    }
}

// ---------------- hyperedge pull: m[e] = (sum_{v in e} xt[v]) * Binv[e] ----------------
__global__ void k_he_pull(const float* __restrict__ xt, const int* __restrict__ colptr,
                          const int* __restrict__ adjC, float* __restrict__ m) {
    int lane = threadIdx.x & 63;
    int wid = blockIdx.x * (blockDim.x >> 6) + (threadIdx.x >> 6);
    int nw  = gridDim.x * (blockDim.x >> 6);
    for (int e = wid; e < N_HE; e += nw) {
        int s = colptr[e], en = colptr[e + 1];
        float acc = 0.0f;
        for (int p = s; p < en; ++p) {
            int v = adjC[p];
            acc += xt[(size_t)v * CH + lane];
        }
        float binv = (en > s) ? 1.0f / (float)(en - s) : 0.0f;
        m[(size_t)e * CH + lane] = acc * binv;
    }
}

// ---------------- node pull + relu(.*Dinv) + transform: out[v] = relu((sum m)*Dinv) @ W + b ----------------
__global__ void k_node_pull_xform(const float* __restrict__ m, const int* __restrict__ rowptr,
                                  const int* __restrict__ adjR, const float* __restrict__ W,
                                  const float* __restrict__ bias, float* __restrict__ out) {
    __shared__ float Wl[CH * CH];
    for (int t = threadIdx.x; t < CH * CH; t += blockDim.x) Wl[t] = W[t];
    __syncthreads();
    int lane = threadIdx.x & 63;
    int wid = blockIdx.x * (blockDim.x >> 6) + (threadIdx.x >> 6);
    int nw  = gridDim.x * (blockDim.x >> 6);
    float bc = bias[lane];
    for (int v = wid; v < N_NODES; v += nw) {
        int s = rowptr[v], en = rowptr[v + 1];
        float acc = 0.0f;
        for (int p = s; p < en; ++p) {
            int c = adjR[p];
            acc += m[(size_t)c * CH + lane];
        }
        float dinv = (en > s) ? 1.0f / (float)(en - s) : 0.0f;
        float h = fmaxf(acc * dinv, 0.0f);
        float o = bc;
#pragma unroll
        for (int k = 0; k < CH; ++k)
            o = fmaf(__shfl(h, k), Wl[k * CH + lane], o);
        out[(size_t)v * CH + lane] = o;   // in-place over bufA is safe: reads only m
    }
}

// ---------------- node pull + relu(.*Dinv) + mean-pool accumulate (batch sorted) ----------------
__global__ void k_node_pull_pool(const float* __restrict__ m, const int* __restrict__ rowptr,
                                 const int* __restrict__ adjR, const int* __restrict__ batch,
                                 float* __restrict__ pooled) {
    int lane = threadIdx.x & 63;
    int wid = blockIdx.x * (blockDim.x >> 6) + (threadIdx.x >> 6);
    int nw  = gridDim.x * (blockDim.x >> 6);
    int per = (N_NODES + nw - 1) / nw;
    int start = wid * per;
    int end = start + per; if (end > N_NODES) end = N_NODES;
    if (start >= end) return;
    float acc = 0.0f;
    int cur = batch[start];
    for (int v = start; v < end; ++v) {
        int s = rowptr[v], en = rowptr[v + 1];
        float sum = 0.0f;
        for (int p = s; p < en; ++p) {
            int c = adjR[p];
            sum += m[(size_t)c * CH + lane];
        }
        float dinv = (en > s) ? 1.0f / (float)(en - s) : 0.0f;
        float val = fmaxf(sum * dinv, 0.0f);
        int b = batch[v];
        if (b != cur) {
            atomicAdd(&pooled[(size_t)cur * CH + lane], acc);
            acc = 0.0f; cur = b;
        }
        acc += val;
    }
    atomicAdd(&pooled[(size_t)cur * CH + lane], acc);
}

// ---------------- final: out[g] = (pooled[g]/max(cnt,1)) . Wfc + bfc ----------------
__global__ void k_final(const float* __restrict__ pooled, const int* __restrict__ gstart,
                        const float* __restrict__ Wfc, const float* __restrict__ bfc,
                        float* __restrict__ out) {
    int g = blockIdx.x;
    int lane = threadIdx.x;  // 64 threads
    float cnt = (float)(gstart[g + 1] - gstart[g]);
    cnt = fmaxf(cnt, 1.0f);
    float s = pooled[(size_t)g * CH + lane] / cnt;
    float p = s * Wfc[lane];
#pragma unroll
    for (int off = 32; off; off >>= 1) p += __shfl_down(p, off);
    if (lane == 0) out[g] = p + bfc[0];
}

extern "C" void kernel_launch(void* const* d_in, const int* in_sizes, int n_in,
                              void* d_out, int out_size, void* d_ws, size_t ws_size,
                              hipStream_t stream) {
    const float* x     = (const float*)d_in[0];
    const int*   ei    = (const int*)d_in[1];
    const int*   batch = (const int*)d_in[2];
    const float* W1    = (const float*)d_in[3];
    const float* b1    = (const float*)d_in[4];
    const float* W2    = (const float*)d_in[5];
    const float* b2    = (const float*)d_in[6];
    const float* Wfc   = (const float*)d_in[7];
    const float* bfc   = (const float*)d_in[8];
    float* out = (float*)d_out;

    const int* row = ei;
    const int* col = ei + NNZ;

    // ---- workspace carve-up (all offsets 256B-aligned) ----
    char* ws = (char*)d_ws;
    size_t off = 0;
    auto carve = [&](size_t bytes) {
        void* p = ws + off;
        off += (bytes + 255) & ~(size_t)255;
        return p;
    };
    float* bufA   = (float*)carve((size_t)N_NODES * CH * sizeof(float));  // 128 MB
    float* bufM   = (float*)carve((size_t)N_HE * CH * sizeof(float));     // 25.6 MB
    int*   adjR   = (int*)carve((size_t)NNZ * sizeof(int));               // 8 MB
    int*   adjC   = (int*)carve((size_t)NNZ * sizeof(int));               // 8 MB
    int*   Dcnt   = (int*)carve((size_t)N_NODES * sizeof(int));
    int*   Bcnt   = (int*)carve((size_t)N_HE * sizeof(int));
    int*   rowptr = (int*)carve((size_t)(N_NODES + 1) * sizeof(int));
    int*   colptr = (int*)carve((size_t)(N_HE + 1) * sizeof(int));
    int*   curR   = (int*)carve((size_t)N_NODES * sizeof(int));
    int*   curC   = (int*)carve((size_t)N_HE * sizeof(int));
    int*   bsR    = (int*)carve(512 * sizeof(int));
    int*   bsC    = (int*)carve(512 * sizeof(int));
    int*   gstart = (int*)carve((size_t)(N_G + 1) * sizeof(int));
    float* pooled = (float*)carve((size_t)N_G * CH * sizeof(float));

    const int nbR = (N_NODES + SCAN_CHUNK - 1) / SCAN_CHUNK;  // 489
    const int nbC = (N_HE + SCAN_CHUNK - 1) / SCAN_CHUNK;     // 98

    // zero only what is accumulated into
    hipMemsetAsync(Dcnt, 0, (size_t)N_NODES * sizeof(int), stream);
    hipMemsetAsync(Bcnt, 0, (size_t)N_HE * sizeof(int), stream);
    hipMemsetAsync(pooled, 0, (size_t)N_G * CH * sizeof(float), stream);

    // build CSR both directions
    k_count<<<2048, 256, 0, stream>>>(row, col, Dcnt, Bcnt);
    k_scan1<<<nbR, SCAN_BLOCK, 0, stream>>>(Dcnt, N_NODES, bsR);
    k_scan2<<<1, 512, 0, stream>>>(bsR, nbR);
    k_scan3<<<nbR, SCAN_BLOCK, 0, stream>>>(Dcnt, N_NODES, bsR, rowptr, curR);
    k_scan1<<<nbC, SCAN_BLOCK, 0, stream>>>(Bcnt, N_HE, bsC);
    k_scan2<<<1, 512, 0, stream>>>(bsC, nbC);
    k_scan3<<<nbC, SCAN_BLOCK, 0, stream>>>(Bcnt, N_HE, bsC, colptr, curC);
    k_place<<<2048, 256, 0, stream>>>(row, col, curR, curC, adjR, adjC);
    k_bounds<<<3, 256, 0, stream>>>(batch, gstart);

    // conv1: xt = x@W1+b1; m = pull(xt)*Binv
    k_transform<<<2048, 256, 0, stream>>>(x, W1, b1, bufA);
    k_he_pull<<<2048, 256, 0, stream>>>(bufA, colptr, adjC, bufM);
    // conv2 input transform fused with conv1's node-pull:
    // bufA = relu(pull(m)*Dinv) @ W2 + b2
    k_node_pull_xform<<<2048, 256, 0, stream>>>(bufM, rowptr, adjR, W2, b2, bufA);
    // conv2: m2 = pull(bufA)*Binv
    k_he_pull<<<2048, 256, 0, stream>>>(bufA, colptr, adjC, bufM);
    // conv2 node-pull fused with mean-pool accumulation
    k_node_pull_pool<<<2048, 256, 0, stream>>>(bufM, rowptr, adjR, batch, pooled);
    k_final<<<N_G, 64, 0, stream>>>(pooled, gstart, Wfc, bfc, out);
}